// Round 8
// baseline (77.844 us; speedup 1.0000x reference)
//
#include <hip/hip_runtime.h>

// ---------------- types / helpers ----------------
using f32x4  = __attribute__((ext_vector_type(4))) float;
using f32x2  = __attribute__((ext_vector_type(2))) float;
using bf16x8 = __attribute__((ext_vector_type(8))) short;

struct __attribute__((packed, aligned(4))) f4a { float x, y, z, w; };  // 4B-aligned float4

__device__ __forceinline__ unsigned short f2bf(float x) {
  unsigned u = __float_as_uint(x);
  u += 0x7FFFu + ((u >> 16) & 1u);   // round-to-nearest-even
  return (unsigned short)(u >> 16);
}
__device__ __forceinline__ float bflo(unsigned u) { return __uint_as_float(u << 16); }
__device__ __forceinline__ float bfhi(unsigned u) { return __uint_as_float(u & 0xffff0000u); }

// pc1: (8,1024,259)  pc2: (8,4096,131)  W1:(384,256) b1:(256) W2:(256,256) b2:(256)
// out: h (8*4096*256 fp32) then xyz2 (8*4096*3 fp32)
#define OUT_H_ELEMS 8388608

#define INSERT(e, j) { \
  bool L2 = ((e) < d2v) || ((e) == d2v && (j) < i2); \
  bool L1 = ((e) < d1 ) || ((e) == d1  && (j) < i1); \
  bool L0 = ((e) < d0 ) || ((e) == d0  && (j) < i0); \
  d2v = L1 ? d1 : (L2 ? (e) : d2v);  i2 = L1 ? i1 : (L2 ? (j) : i2); \
  d1  = L0 ? d0 : (L1 ? (e) : d1 );  i1 = L0 ? i0 : (L1 ? (j) : i1); \
  d0  = L0 ? (e) : d0;               i0 = L0 ? (j) : i0; }

#define CHAIN_UPD(dd, D0, D1, D2, I0, I1, I2, c) { \
  bool l2 = (dd) < D2, l1 = (dd) < D1, l0 = (dd) < D0; \
  D2 = l1 ? D1 : (l2 ? (dd) : D2);  I2 = l1 ? I1 : (l2 ? (c) : I2); \
  D1 = l0 ? D0 : (l1 ? (dd) : D1);  I1 = l0 ? I0 : (l1 ? (c) : I1); \
  D0 = l0 ? (dd) : D0;              I0 = l0 ? (c) : I0; }

// ---------------- prep: P1 bf16 table + weight transposes + xyz1 SoA ----------------
// [0, 524288): pc1 feats -> P1 bf16 [8192][256]
// [524288, 622592): W1t ; [622592, 688128): W2t
// [688128, 712704): xyz1 SoA [8][3][1024] f32
__global__ void prep(const float* __restrict__ pc1,
                     const float* __restrict__ W1, const float* __restrict__ W2,
                     unsigned short* __restrict__ W1t, unsigned short* __restrict__ W2t,
                     float* __restrict__ soa, unsigned short* __restrict__ P1) {
  int tid = blockIdx.x * 256 + threadIdx.x;
  if (tid < 524288) {
    int r = tid >> 6, l = tid & 63;
    const float* src = pc1 + (size_t)r * 259 + 3 + l * 4;
    ushort4 v;
    v.x = f2bf(src[0]); v.y = f2bf(src[1]); v.z = f2bf(src[2]); v.w = f2bf(src[3]);
    *(ushort4*)(P1 + ((size_t)r << 8) + l * 4) = v;
  } else if (tid < 622592) {
    int id = tid - 524288;                     // W1t[n][k] = W1[k][n], 256x384
    int n = id / 384, k = id - n * 384;
    W1t[id] = f2bf(W1[k * 256 + n]);
  } else if (tid < 688128) {
    int id2 = tid - 622592;                    // W2t[n][k] = W2[k][n], 256x256
    int n = id2 >> 8, k = id2 & 255;
    W2t[id2] = f2bf(W2[k * 256 + n]);
  } else if (tid < 712704) {
    int id = tid - 688128;                     // soa[b][coord][r] = xyz1
    int b = id / 3072, rem = id - b * 3072;
    int coord = rem >> 10, r = rem & 1023;
    soa[id] = pc1[(size_t)b * (1024 * 259) + (size_t)r * 259 + coord];
  }
}

// ---------------- front: 3-NN + inline interp + pc2 cols + xyz2 ----------------
// 2048 blocks x 256 threads; 16 queries/block, 16 lanes/query.
__global__ __launch_bounds__(256, 8) void front(
    const float* __restrict__ pc2, const float* __restrict__ soa,
    const unsigned short* __restrict__ P1,
    unsigned short* __restrict__ A1, float* __restrict__ xyzo) {
#pragma clang fp contract(off)
  __shared__ __align__(16) float s3[3][1024];
  const int t = threadIdx.x;
  const int blk = (blockIdx.x & 7) * 256 + (blockIdx.x >> 3);   // bijective (2048 = 8*256)
  const int b = blk >> 8;
  const int chunk = blk & 255;

  // --- stage SoA xyz1 into LDS: 3 coalesced f32x4 per thread ---
  const f32x4* gsoa = (const f32x4*)(soa + b * 3072);
  f32x4* ls = (f32x4*)&s3[0][0];
  #pragma unroll
  for (int j = 0; j < 3; ++j) ls[j * 256 + t] = gsoa[j * 256 + t];
  __syncthreads();

  const int q = chunk * 16 + (t >> 4);
  const int sub = t & 15;
  const size_t qrow = (size_t)b * 4096 + q;
  const float* qp = pc2 + qrow * 131;
  const float qx = qp[0], qy = qp[1], qz = qp[2];
  const f32x2 qx2 = {qx, qx}, qy2 = {qy, qy}, qz2 = {qz, qz};

  // 4 independent top-3 chains, one per element of each float4 quad
  float dA0 = 3.4e38f, dA1 = 3.4e38f, dA2 = 3.4e38f;  int iA0 = -1, iA1 = -1, iA2 = -1;
  float dB0 = 3.4e38f, dB1 = 3.4e38f, dB2 = 3.4e38f;  int iB0 = -1, iB1 = -1, iB2 = -1;
  float dC0 = 3.4e38f, dC1 = 3.4e38f, dC2 = 3.4e38f;  int iC0 = -1, iC1 = -1, iC2 = -1;
  float dD0 = 3.4e38f, dD1 = 3.4e38f, dD2 = 3.4e38f;  int iD0 = -1, iD1 = -1, iD2 = -1;

  const f32x4* sXf = (const f32x4*)&s3[0][0];
  const f32x4* sYf = (const f32x4*)&s3[1][0];
  const f32x4* sZf = (const f32x4*)&s3[2][0];

  #pragma unroll 4
  for (int it = 0; it < 16; ++it) {
    const int m = it * 16 + sub;       // quad index 0..255
    f32x4 xv = sXf[m], yv = sYf[m], zv = sZf[m];
    // packed exact math, numpy order: (dx*dx + dy*dy) + dz*dz, contract(off)
    f32x2 xlo = {xv[0], xv[1]}, xhi = {xv[2], xv[3]};
    f32x2 ylo = {yv[0], yv[1]}, yhi = {yv[2], yv[3]};
    f32x2 zlo = {zv[0], zv[1]}, zhi = {zv[2], zv[3]};
    f32x2 dxl = qx2 - xlo, dyl = qy2 - ylo, dzl = qz2 - zlo;
    f32x2 dxh = qx2 - xhi, dyh = qy2 - yhi, dzh = qz2 - zhi;
    f32x2 dl = (dxl * dxl + dyl * dyl) + dzl * dzl;
    f32x2 dh = (dxh * dxh + dyh * dyh) + dzh * dzh;
    const int c0 = m * 4;
    CHAIN_UPD(dl[0], dA0, dA1, dA2, iA0, iA1, iA2, c0)
    CHAIN_UPD(dl[1], dB0, dB1, dB2, iB0, iB1, iB2, c0 + 1)
    CHAIN_UPD(dh[0], dC0, dC1, dC2, iC0, iC1, iC2, c0 + 2)
    CHAIN_UPD(dh[1], dD0, dD1, dD2, iD0, iD1, iD2, c0 + 3)
  }

  // merge chains B,C,D into A (exact lexicographic)
  float d0 = dA0, d1 = dA1, d2v = dA2;  int i0 = iA0, i1 = iA1, i2 = iA2;
  INSERT(dB0, iB0) INSERT(dB1, iB1) INSERT(dB2, iB2)
  INSERT(dC0, iC0) INSERT(dC1, iC1) INSERT(dC2, iC2)
  INSERT(dD0, iD0) INSERT(dD1, iD1) INSERT(dD2, iD2)
  // merge across the 16 lanes of this query; all lanes end identical
  #pragma unroll
  for (int stp = 1; stp <= 8; stp <<= 1) {
    float f0 = __shfl_xor(d0, stp, 64);  int k0 = __shfl_xor(i0, stp, 64);
    float f1 = __shfl_xor(d1, stp, 64);  int k1 = __shfl_xor(i1, stp, 64);
    float f2 = __shfl_xor(d2v, stp, 64); int k2 = __shfl_xor(i2, stp, 64);
    INSERT(f0, k0) INSERT(f1, k1) INSERT(f2, k2)
  }
  // weights (exact reference order)
  float t0 = fmaxf(d0, 1e-7f), t1 = fmaxf(d1, 1e-7f), t2 = fmaxf(d2v, 1e-7f);
  float r0 = 1.0f / t0, r1 = 1.0f / t1, r2 = 1.0f / t2;
  float nrm = (r0 + r1) + r2;
  float w0v = r0 / nrm, w1v = r1 / nrm, w2v = r2 / nrm;

  if (sub == 1) {
    xyzo[qrow * 3 + 0] = qx; xyzo[qrow * 3 + 1] = qy; xyzo[qrow * 3 + 2] = qz;
  }

  // --- inline interp from P1 bf16 (32B-aligned): lane covers cols [sub*16, +16) ---
  const unsigned short* P1b = P1 + ((size_t)b << 18);
  const uint4* g0 = (const uint4*)(P1b + (i0 << 8) + sub * 16);
  const uint4* g1 = (const uint4*)(P1b + (i1 << 8) + sub * 16);
  const uint4* g2 = (const uint4*)(P1b + (i2 << 8) + sub * 16);
  unsigned short* arow = A1 + qrow * 384 + sub * 16;
  #pragma unroll
  for (int h = 0; h < 2; ++h) {
    uint4 u0 = g0[h], u1 = g1[h], u2 = g2[h];
    unsigned ov[4];
    const unsigned* a0 = (const unsigned*)&u0;
    const unsigned* a1 = (const unsigned*)&u1;
    const unsigned* a2 = (const unsigned*)&u2;
    #pragma unroll
    for (int c = 0; c < 4; ++c) {
      float lo = fmaf(w2v, bflo(a2[c]), fmaf(w1v, bflo(a1[c]), w0v * bflo(a0[c])));
      float hi = fmaf(w2v, bfhi(a2[c]), fmaf(w1v, bfhi(a1[c]), w0v * bfhi(a0[c])));
      ov[c] = (unsigned)f2bf(lo) | ((unsigned)f2bf(hi) << 16);
    }
    *(uint4*)(arow + h * 8) = *(const uint4*)ov;
  }
  // --- pc2 feature cols: lane covers A1 cols [256+sub*8, +8) ---
  const float* gp = qp + 3 + sub * 8;
  unsigned short* arow2 = A1 + qrow * 384 + 256 + sub * 8;
  #pragma unroll
  for (int c4 = 0; c4 < 2; ++c4) {
    f4a v = *(const f4a*)(gp + c4 * 4);
    ushort4 ov;
    ov.x = f2bf(v.x); ov.y = f2bf(v.y); ov.z = f2bf(v.z); ov.w = f2bf(v.w);
    *(ushort4*)(arow2 + c4 * 4) = ov;
  }
}

// ---------------- fused two-layer MFMA GEMM, direct-operand version ----------------
// 64KB LDS (Hbuf only) -> 2 blocks/CU. Phase 1 barrier-free: A/B fragments loaded
// straight from global (W is L1/L2-resident; A lines fully consumed per k-tile).
__global__ __launch_bounds__(512, 4) void fused_gemm(
    const unsigned short* __restrict__ A1, const unsigned short* __restrict__ W1t,
    const unsigned short* __restrict__ W2t, const float* __restrict__ b1,
    const float* __restrict__ b2, float* __restrict__ out) {
  extern __shared__ char lds[];
  char* Hbuf = lds;                       // 64K: H tile 128x256 bf16, row stride 512B

  const int t = threadIdx.x, lane = t & 63, wv = t >> 6;
  const int wm = wv >> 2, wn = wv & 3;    // 2 x 4 wave grid, each 64x64 output
  const int m0 = blockIdx.x * 128;
  const int lrow = lane & 15;             // fragment row within 16
  const int klane = (lane >> 4) * 8;      // fragment k-offset (elements)

  const unsigned short* baseA  = A1  + (size_t)(m0 + wm * 64 + lrow) * 384 + klane;
  const unsigned short* baseB1 = W1t + (size_t)(wn * 64 + lrow) * 384 + klane;
  const unsigned short* baseB2 = W2t + (size_t)(wn * 64 + lrow) * 256 + klane;

  f32x4 zero = {0.f, 0.f, 0.f, 0.f};
  f32x4 acc[4][4];
  #pragma unroll
  for (int i = 0; i < 4; ++i)
    #pragma unroll
    for (int j = 0; j < 4; ++j) acc[i][j] = zero;

  // ---- phase 1: 6 k-tiles of 64, no barriers, direct operand loads ----
  #pragma unroll
  for (int kt = 0; kt < 6; ++kt) {
    #pragma unroll
    for (int ks = 0; ks < 2; ++ks) {
      const int ko = kt * 64 + ks * 32;
      bf16x8 af[4], bfr[4];
      #pragma unroll
      for (int i = 0; i < 4; ++i)
        af[i] = *(const bf16x8*)(const void*)(baseA + i * (16 * 384) + ko);
      #pragma unroll
      for (int j = 0; j < 4; ++j)
        bfr[j] = *(const bf16x8*)(const void*)(baseB1 + j * (16 * 384) + ko);
      #pragma unroll
      for (int i = 0; i < 4; ++i)
        #pragma unroll
        for (int j = 0; j < 4; ++j)
          acc[i][j] = __builtin_amdgcn_mfma_f32_16x16x32_bf16(af[i], bfr[j], acc[i][j], 0, 0, 0);
    }
  }

  // ---- phase-1 epilogue: relu+bias -> bf16 -> Hbuf (swizzled) ----
  const int colb = wn * 64 + lrow;
  const int rowb = wm * 64 + ((lane >> 4) << 2);
  #pragma unroll
  for (int ni = 0; ni < 4; ++ni) {
    float bv = b1[colb + ni * 16];
    #pragma unroll
    for (int mi = 0; mi < 4; ++mi) {
      #pragma unroll
      for (int r = 0; r < 4; ++r) {
        float v = fmaxf(acc[mi][ni][r] + bv, 0.0f);
        int row = rowb + mi * 16 + r, col = colb + ni * 16;
        *(unsigned short*)(Hbuf + row * 512 + ((col * 2) ^ ((row & 15) << 4))) = f2bf(v);
        acc[mi][ni][r] = 0.0f;
      }
    }
  }
  __syncthreads();

  // ---- phase 2: 4 k-tiles of 64, A = Hbuf (LDS), B = W2t direct ----
  #pragma unroll
  for (int kt = 0; kt < 4; ++kt) {
    #pragma unroll
    for (int ks = 0; ks < 2; ++ks) {
      const int sl = ks * 4 + (lane >> 4);
      const int ko = kt * 64 + ks * 32;
      bf16x8 af[4], bfr[4];
      #pragma unroll
      for (int i = 0; i < 4; ++i) {
        int hr = wm * 64 + i * 16 + lrow;
        af[i] = *(const bf16x8*)(void*)(Hbuf + hr * 512 + ((kt * 128 + sl * 16) ^ ((hr & 15) << 4)));
      }
      #pragma unroll
      for (int j = 0; j < 4; ++j)
        bfr[j] = *(const bf16x8*)(const void*)(baseB2 + j * (16 * 256) + ko);
      #pragma unroll
      for (int i = 0; i < 4; ++i)
        #pragma unroll
        for (int j = 0; j < 4; ++j)
          acc[i][j] = __builtin_amdgcn_mfma_f32_16x16x32_bf16(af[i], bfr[j], acc[i][j], 0, 0, 0);
    }
  }

  // ---- phase-2 epilogue: relu+bias -> direct stores (4 rows x 64B per wave-store) ----
  #pragma unroll
  for (int ni = 0; ni < 4; ++ni) {
    float bv = b2[colb + ni * 16];
    #pragma unroll
    for (int mi = 0; mi < 4; ++mi) {
      #pragma unroll
      for (int r = 0; r < 4; ++r) {
        float v = fmaxf(acc[mi][ni][r] + bv, 0.0f);
        out[(size_t)(m0 + rowb + mi * 16 + r) * 256 + colb + ni * 16] = v;
      }
    }
  }
}

// ---------------- launch ----------------
extern "C" void kernel_launch(void* const* d_in, const int* in_sizes, int n_in,
                              void* d_out, int out_size, void* d_ws, size_t ws_size,
                              hipStream_t stream) {
  const float* pc1 = (const float*)d_in[0];
  const float* pc2 = (const float*)d_in[1];
  const float* W1  = (const float*)d_in[2];
  const float* b1  = (const float*)d_in[3];
  const float* W2  = (const float*)d_in[4];
  const float* b2  = (const float*)d_in[5];
  float* out = (float*)d_out;
  char* ws = (char*)d_ws;

  unsigned short* W1t = (unsigned short*)(ws + 0);        // 256x384 bf16
  unsigned short* W2t = (unsigned short*)(ws + 196608);   // 256x256 bf16
  float*          soa = (float*)(ws + 327680);            // 8x3x1024 f32
  unsigned short* P1  = (unsigned short*)(ws + 425984);   // 8x1024x256 bf16
  unsigned short* A1  = (unsigned short*)(ws + 4620288);  // 32768x384 bf16
  // ws usage ends at 29,786,112 bytes

  hipFuncSetAttribute((const void*)fused_gemm, hipFuncAttributeMaxDynamicSharedMemorySize, 65536);

  prep<<<2784, 256, 0, stream>>>(pc1, W1, W2, W1t, W2t, soa, P1);
  front<<<2048, 256, 0, stream>>>(pc2, soa, P1, A1, out + OUT_H_ELEMS);
  fused_gemm<<<256, 512, 65536, stream>>>(A1, W1t, W2t, b1, b2, out);
}

// Round 9
// 68.630 us; speedup vs baseline: 1.1343x; 1.1343x over previous
//
#include <hip/hip_runtime.h>

// ---------------- types / helpers ----------------
using f32x4  = __attribute__((ext_vector_type(4))) float;
using f32x2  = __attribute__((ext_vector_type(2))) float;
using bf16x8 = __attribute__((ext_vector_type(8))) short;

struct __attribute__((packed, aligned(4))) f4a { float x, y, z, w; };  // 4B-aligned float4

__device__ __forceinline__ unsigned short f2bf(float x) {
  unsigned u = __float_as_uint(x);
  u += 0x7FFFu + ((u >> 16) & 1u);   // round-to-nearest-even
  return (unsigned short)(u >> 16);
}
__device__ __forceinline__ float bflo(unsigned u) { return __uint_as_float(u << 16); }
__device__ __forceinline__ float bfhi(unsigned u) { return __uint_as_float(u & 0xffff0000u); }

// pc1: (8,1024,259)  pc2: (8,4096,131)  W1:(384,256) b1:(256) W2:(256,256) b2:(256)
// out: h (8*4096*256 fp32) then xyz2 (8*4096*3 fp32)
#define OUT_H_ELEMS 8388608

#define INSERT(e, j) { \
  bool L2 = ((e) < d2v) || ((e) == d2v && (j) < i2); \
  bool L1 = ((e) < d1 ) || ((e) == d1  && (j) < i1); \
  bool L0 = ((e) < d0 ) || ((e) == d0  && (j) < i0); \
  d2v = L1 ? d1 : (L2 ? (e) : d2v);  i2 = L1 ? i1 : (L2 ? (j) : i2); \
  d1  = L0 ? d0 : (L1 ? (e) : d1 );  i1 = L0 ? i0 : (L1 ? (j) : i1); \
  d0  = L0 ? (e) : d0;               i0 = L0 ? (j) : i0; }

#define CHAIN_UPD(dd, D0, D1, D2, I0, I1, I2, c) { \
  bool l2 = (dd) < D2, l1 = (dd) < D1, l0 = (dd) < D0; \
  D2 = l1 ? D1 : (l2 ? (dd) : D2);  I2 = l1 ? I1 : (l2 ? (c) : I2); \
  D1 = l0 ? D0 : (l1 ? (dd) : D1);  I1 = l0 ? I0 : (l1 ? (c) : I1); \
  D0 = l0 ? (dd) : D0;              I0 = l0 ? (c) : I0; }

// ---------------- prep: P1 bf16 table + weight transposes + xyz1 SoA ----------------
__global__ void prep(const float* __restrict__ pc1,
                     const float* __restrict__ W1, const float* __restrict__ W2,
                     unsigned short* __restrict__ W1t, unsigned short* __restrict__ W2t,
                     float* __restrict__ soa, unsigned short* __restrict__ P1) {
  int tid = blockIdx.x * 256 + threadIdx.x;
  if (tid < 524288) {
    int r = tid >> 6, l = tid & 63;
    const float* src = pc1 + (size_t)r * 259 + 3 + l * 4;
    ushort4 v;
    v.x = f2bf(src[0]); v.y = f2bf(src[1]); v.z = f2bf(src[2]); v.w = f2bf(src[3]);
    *(ushort4*)(P1 + ((size_t)r << 8) + l * 4) = v;
  } else if (tid < 622592) {
    int id = tid - 524288;                     // W1t[n][k] = W1[k][n], 256x384
    int n = id / 384, k = id - n * 384;
    W1t[id] = f2bf(W1[k * 256 + n]);
  } else if (tid < 688128) {
    int id2 = tid - 622592;                    // W2t[n][k] = W2[k][n], 256x256
    int n = id2 >> 8, k = id2 & 255;
    W2t[id2] = f2bf(W2[k * 256 + n]);
  } else if (tid < 712704) {
    int id = tid - 688128;                     // soa[b][coord][r] = xyz1
    int b = id / 3072, rem = id - b * 3072;
    int coord = rem >> 10, r = rem & 1023;
    soa[id] = pc1[(size_t)b * (1024 * 259) + (size_t)r * 259 + coord];
  }
}

// ---------------- front: 3-NN + inline interp + pc2 cols + xyz2 (unchanged) ----------------
__global__ __launch_bounds__(256, 8) void front(
    const float* __restrict__ pc2, const float* __restrict__ soa,
    const unsigned short* __restrict__ P1,
    unsigned short* __restrict__ A1, float* __restrict__ xyzo) {
#pragma clang fp contract(off)
  __shared__ __align__(16) float s3[3][1024];
  const int t = threadIdx.x;
  const int blk = (blockIdx.x & 7) * 256 + (blockIdx.x >> 3);   // bijective (2048 = 8*256)
  const int b = blk >> 8;
  const int chunk = blk & 255;

  const f32x4* gsoa = (const f32x4*)(soa + b * 3072);
  f32x4* ls = (f32x4*)&s3[0][0];
  #pragma unroll
  for (int j = 0; j < 3; ++j) ls[j * 256 + t] = gsoa[j * 256 + t];
  __syncthreads();

  const int q = chunk * 16 + (t >> 4);
  const int sub = t & 15;
  const size_t qrow = (size_t)b * 4096 + q;
  const float* qp = pc2 + qrow * 131;
  const float qx = qp[0], qy = qp[1], qz = qp[2];
  const f32x2 qx2 = {qx, qx}, qy2 = {qy, qy}, qz2 = {qz, qz};

  float dA0 = 3.4e38f, dA1 = 3.4e38f, dA2 = 3.4e38f;  int iA0 = -1, iA1 = -1, iA2 = -1;
  float dB0 = 3.4e38f, dB1 = 3.4e38f, dB2 = 3.4e38f;  int iB0 = -1, iB1 = -1, iB2 = -1;
  float dC0 = 3.4e38f, dC1 = 3.4e38f, dC2 = 3.4e38f;  int iC0 = -1, iC1 = -1, iC2 = -1;
  float dD0 = 3.4e38f, dD1 = 3.4e38f, dD2 = 3.4e38f;  int iD0 = -1, iD1 = -1, iD2 = -1;

  const f32x4* sXf = (const f32x4*)&s3[0][0];
  const f32x4* sYf = (const f32x4*)&s3[1][0];
  const f32x4* sZf = (const f32x4*)&s3[2][0];

  #pragma unroll 4
  for (int it = 0; it < 16; ++it) {
    const int m = it * 16 + sub;
    f32x4 xv = sXf[m], yv = sYf[m], zv = sZf[m];
    f32x2 xlo = {xv[0], xv[1]}, xhi = {xv[2], xv[3]};
    f32x2 ylo = {yv[0], yv[1]}, yhi = {yv[2], yv[3]};
    f32x2 zlo = {zv[0], zv[1]}, zhi = {zv[2], zv[3]};
    f32x2 dxl = qx2 - xlo, dyl = qy2 - ylo, dzl = qz2 - zlo;
    f32x2 dxh = qx2 - xhi, dyh = qy2 - yhi, dzh = qz2 - zhi;
    f32x2 dl = (dxl * dxl + dyl * dyl) + dzl * dzl;
    f32x2 dh = (dxh * dxh + dyh * dyh) + dzh * dzh;
    const int c0 = m * 4;
    CHAIN_UPD(dl[0], dA0, dA1, dA2, iA0, iA1, iA2, c0)
    CHAIN_UPD(dl[1], dB0, dB1, dB2, iB0, iB1, iB2, c0 + 1)
    CHAIN_UPD(dh[0], dC0, dC1, dC2, iC0, iC1, iC2, c0 + 2)
    CHAIN_UPD(dh[1], dD0, dD1, dD2, iD0, iD1, iD2, c0 + 3)
  }

  float d0 = dA0, d1 = dA1, d2v = dA2;  int i0 = iA0, i1 = iA1, i2 = iA2;
  INSERT(dB0, iB0) INSERT(dB1, iB1) INSERT(dB2, iB2)
  INSERT(dC0, iC0) INSERT(dC1, iC1) INSERT(dC2, iC2)
  INSERT(dD0, iD0) INSERT(dD1, iD1) INSERT(dD2, iD2)
  #pragma unroll
  for (int stp = 1; stp <= 8; stp <<= 1) {
    float f0 = __shfl_xor(d0, stp, 64);  int k0 = __shfl_xor(i0, stp, 64);
    float f1 = __shfl_xor(d1, stp, 64);  int k1 = __shfl_xor(i1, stp, 64);
    float f2 = __shfl_xor(d2v, stp, 64); int k2 = __shfl_xor(i2, stp, 64);
    INSERT(f0, k0) INSERT(f1, k1) INSERT(f2, k2)
  }
  float t0 = fmaxf(d0, 1e-7f), t1 = fmaxf(d1, 1e-7f), t2 = fmaxf(d2v, 1e-7f);
  float r0 = 1.0f / t0, r1 = 1.0f / t1, r2 = 1.0f / t2;
  float nrm = (r0 + r1) + r2;
  float w0v = r0 / nrm, w1v = r1 / nrm, w2v = r2 / nrm;

  if (sub == 1) {
    xyzo[qrow * 3 + 0] = qx; xyzo[qrow * 3 + 1] = qy; xyzo[qrow * 3 + 2] = qz;
  }

  const unsigned short* P1b = P1 + ((size_t)b << 18);
  const uint4* g0 = (const uint4*)(P1b + (i0 << 8) + sub * 16);
  const uint4* g1 = (const uint4*)(P1b + (i1 << 8) + sub * 16);
  const uint4* g2 = (const uint4*)(P1b + (i2 << 8) + sub * 16);
  unsigned short* arow = A1 + qrow * 384 + sub * 16;
  #pragma unroll
  for (int h = 0; h < 2; ++h) {
    uint4 u0 = g0[h], u1 = g1[h], u2 = g2[h];
    unsigned ov[4];
    const unsigned* a0 = (const unsigned*)&u0;
    const unsigned* a1 = (const unsigned*)&u1;
    const unsigned* a2 = (const unsigned*)&u2;
    #pragma unroll
    for (int c = 0; c < 4; ++c) {
      float lo = fmaf(w2v, bflo(a2[c]), fmaf(w1v, bflo(a1[c]), w0v * bflo(a0[c])));
      float hi = fmaf(w2v, bfhi(a2[c]), fmaf(w1v, bfhi(a1[c]), w0v * bfhi(a0[c])));
      ov[c] = (unsigned)f2bf(lo) | ((unsigned)f2bf(hi) << 16);
    }
    *(uint4*)(arow + h * 8) = *(const uint4*)ov;
  }
  const float* gp = qp + 3 + sub * 8;
  unsigned short* arow2 = A1 + qrow * 384 + 256 + sub * 8;
  #pragma unroll
  for (int c4 = 0; c4 < 2; ++c4) {
    f4a v = *(const f4a*)(gp + c4 * 4);
    ushort4 ov;
    ov.x = f2bf(v.x); ov.y = f2bf(v.y); ov.z = f2bf(v.z); ov.w = f2bf(v.w);
    *(ushort4*)(arow2 + c4 * 4) = ov;
  }
}

// ---------------- fused two-layer MFMA GEMM, BM=64 ----------------
// 512 blocks x 256 threads (4 waves, wave n-split). LDS 48KB static -> 2 blocks/CU.
// Phase 1: A staged in LDS (8KB dbuf, XOR swizzle, 1 barrier/kt); B=W1t streamed from L2.
// Phase 2: A = Hbuf (32KB LDS), B=W2t streamed. H never touches HBM.
__global__ __launch_bounds__(256, 2) void fused_gemm(
    const unsigned short* __restrict__ A1, const unsigned short* __restrict__ W1t,
    const unsigned short* __restrict__ W2t, const float* __restrict__ b1,
    const float* __restrict__ b2, float* __restrict__ out) {
  __shared__ char Ast[16384];     // 2 x 8KB A-tile [64][64] bf16, swizzled
  __shared__ char Hbuf[32768];    // H tile [64][256] bf16, row stride 512B, swizzled

  const int t = threadIdx.x, lane = t & 63, wn = t >> 6;   // 4 waves, n-split
  const int m0 = blockIdx.x * 64;
  const int lrow = lane & 15;
  const int kslot = lane >> 4;          // 0..3
  const int klane = kslot * 8;
  const int xorl = (lrow & 7) << 4;     // per-lane A-read XOR term

  // A staging: 8KB / 256 threads = 2 x 16B per thread
  const int srow = t >> 2, ss0 = (t & 3) * 2;
  const unsigned short* gA = A1 + (size_t)(m0 + srow) * 384 + ss0 * 8;
  const int wo0 = srow * 128 + (((ss0    ) * 16) ^ ((srow & 7) << 4));
  const int wo1 = srow * 128 + (((ss0 + 1) * 16) ^ ((srow & 7) << 4));

  const unsigned short* baseB1 = W1t + (size_t)(wn * 64 + lrow) * 384 + klane;
  const unsigned short* baseB2 = W2t + (size_t)(wn * 64 + lrow) * 256 + klane;

  f32x4 zero = {0.f, 0.f, 0.f, 0.f};
  f32x4 acc[4][4];
  #pragma unroll
  for (int i = 0; i < 4; ++i)
    #pragma unroll
    for (int j = 0; j < 4; ++j) acc[i][j] = zero;

  // prologue: stage k-tile 0
  f32x4 ra0 = *(const f32x4*)(const void*)(gA);
  f32x4 ra1 = *(const f32x4*)(const void*)(gA + 8);
  *(f32x4*)(void*)(Ast + wo0) = ra0;
  *(f32x4*)(void*)(Ast + wo1) = ra1;
  __syncthreads();

  // ---- phase 1: 6 k-tiles of 64 ----
  int cur = 0;
  #pragma unroll
  for (int kt = 0; kt < 6; ++kt) {
    if (kt < 5) {
      ra0 = *(const f32x4*)(const void*)(gA + (kt + 1) * 64);
      ra1 = *(const f32x4*)(const void*)(gA + (kt + 1) * 64 + 8);
    }
    char* ab = Ast + cur * 8192;
    #pragma unroll
    for (int ks = 0; ks < 2; ++ks) {
      const int sl = ks * 4 + kslot;
      const int ko = kt * 64 + ks * 32;
      bf16x8 af[4], bfr[4];
      #pragma unroll
      for (int j = 0; j < 4; ++j)
        bfr[j] = *(const bf16x8*)(const void*)(baseB1 + j * (16 * 384) + ko);
      #pragma unroll
      for (int i = 0; i < 4; ++i)
        af[i] = *(const bf16x8*)(void*)(ab + (i * 16 + lrow) * 128 + ((sl * 16) ^ xorl));
      #pragma unroll
      for (int i = 0; i < 4; ++i)
        #pragma unroll
        for (int j = 0; j < 4; ++j)
          acc[i][j] = __builtin_amdgcn_mfma_f32_16x16x32_bf16(af[i], bfr[j], acc[i][j], 0, 0, 0);
    }
    if (kt < 5) {
      char* wb = Ast + (cur ^ 1) * 8192;
      *(f32x4*)(void*)(wb + wo0) = ra0;
      *(f32x4*)(void*)(wb + wo1) = ra1;
    }
    __syncthreads();
    cur ^= 1;
  }

  // ---- phase-1 epilogue: relu+bias -> bf16 -> Hbuf (swizzled) ----
  const int colb = wn * 64 + lrow;
  const int rowb = kslot * 4;
  #pragma unroll
  for (int ni = 0; ni < 4; ++ni) {
    float bv = b1[colb + ni * 16];
    #pragma unroll
    for (int mi = 0; mi < 4; ++mi) {
      #pragma unroll
      for (int r = 0; r < 4; ++r) {
        float v = fmaxf(acc[mi][ni][r] + bv, 0.0f);
        int row = rowb + mi * 16 + r, col = colb + ni * 16;
        *(unsigned short*)(Hbuf + row * 512 + ((col * 2) ^ ((row & 15) << 4))) = f2bf(v);
        acc[mi][ni][r] = 0.0f;
      }
    }
  }
  __syncthreads();

  // ---- phase 2: 4 k-tiles of 64, A = Hbuf, B = W2t streamed ----
  #pragma unroll
  for (int kt = 0; kt < 4; ++kt) {
    #pragma unroll
    for (int ks = 0; ks < 2; ++ks) {
      const int sl = ks * 4 + kslot;
      const int ko = kt * 64 + ks * 32;
      bf16x8 af[4], bfr[4];
      #pragma unroll
      for (int j = 0; j < 4; ++j)
        bfr[j] = *(const bf16x8*)(const void*)(baseB2 + j * (16 * 256) + ko);
      #pragma unroll
      for (int i = 0; i < 4; ++i) {
        int hr = i * 16 + lrow;
        af[i] = *(const bf16x8*)(void*)(Hbuf + hr * 512 + ((kt * 128 + sl * 16) ^ ((lrow & 15) << 4)));
      }
      #pragma unroll
      for (int i = 0; i < 4; ++i)
        #pragma unroll
        for (int j = 0; j < 4; ++j)
          acc[i][j] = __builtin_amdgcn_mfma_f32_16x16x32_bf16(af[i], bfr[j], acc[i][j], 0, 0, 0);
    }
  }

  // ---- phase-2 epilogue: relu+bias -> direct f32 stores ----
  #pragma unroll
  for (int ni = 0; ni < 4; ++ni) {
    float bv = b2[colb + ni * 16];
    #pragma unroll
    for (int mi = 0; mi < 4; ++mi) {
      #pragma unroll
      for (int r = 0; r < 4; ++r) {
        float v = fmaxf(acc[mi][ni][r] + bv, 0.0f);
        out[(size_t)(m0 + rowb + mi * 16 + r) * 256 + colb + ni * 16] = v;
      }
    }
  }
}

// ---------------- launch ----------------
extern "C" void kernel_launch(void* const* d_in, const int* in_sizes, int n_in,
                              void* d_out, int out_size, void* d_ws, size_t ws_size,
                              hipStream_t stream) {
  const float* pc1 = (const float*)d_in[0];
  const float* pc2 = (const float*)d_in[1];
  const float* W1  = (const float*)d_in[2];
  const float* b1  = (const float*)d_in[3];
  const float* W2  = (const float*)d_in[4];
  const float* b2  = (const float*)d_in[5];
  float* out = (float*)d_out;
  char* ws = (char*)d_ws;

  unsigned short* W1t = (unsigned short*)(ws + 0);        // 256x384 bf16
  unsigned short* W2t = (unsigned short*)(ws + 196608);   // 256x256 bf16
  float*          soa = (float*)(ws + 327680);            // 8x3x1024 f32
  unsigned short* P1  = (unsigned short*)(ws + 425984);   // 8x1024x256 bf16
  unsigned short* A1  = (unsigned short*)(ws + 4620288);  // 32768x384 bf16
  // ws usage ends at 29,786,112 bytes

  prep<<<2784, 256, 0, stream>>>(pc1, W1, W2, W1t, W2t, soa, P1);
  front<<<2048, 256, 0, stream>>>(pc2, soa, P1, A1, out + OUT_H_ELEMS);
  fused_gemm<<<512, 256, 0, stream>>>(A1, W1t, W2t, b1, b2, out);
}

// Round 10
// 65.834 us; speedup vs baseline: 1.1824x; 1.0425x over previous
//
#include <hip/hip_runtime.h>

// ---------------- types / helpers ----------------
using f32x4  = __attribute__((ext_vector_type(4))) float;
using f32x2  = __attribute__((ext_vector_type(2))) float;
using bf16x8 = __attribute__((ext_vector_type(8))) short;

struct __attribute__((packed, aligned(4))) f4a { float x, y, z, w; };  // 4B-aligned float4

__device__ __forceinline__ unsigned short f2bf(float x) {
  unsigned u = __float_as_uint(x);
  u += 0x7FFFu + ((u >> 16) & 1u);   // round-to-nearest-even
  return (unsigned short)(u >> 16);
}
__device__ __forceinline__ float bflo(unsigned u) { return __uint_as_float(u << 16); }
__device__ __forceinline__ float bfhi(unsigned u) { return __uint_as_float(u & 0xffff0000u); }

// pc1: (8,1024,259)  pc2: (8,4096,131)  W1:(384,256) b1:(256) W2:(256,256) b2:(256)
// out: h (8*4096*256 fp32) then xyz2 (8*4096*3 fp32)
#define OUT_H_ELEMS 8388608

#define INSERT(e, j) { \
  bool L2 = ((e) < d2v) || ((e) == d2v && (j) < i2); \
  bool L1 = ((e) < d1 ) || ((e) == d1  && (j) < i1); \
  bool L0 = ((e) < d0 ) || ((e) == d0  && (j) < i0); \
  d2v = L1 ? d1 : (L2 ? (e) : d2v);  i2 = L1 ? i1 : (L2 ? (j) : i2); \
  d1  = L0 ? d0 : (L1 ? (e) : d1 );  i1 = L0 ? i0 : (L1 ? (j) : i1); \
  d0  = L0 ? (e) : d0;               i0 = L0 ? (j) : i0; }

#define CHAIN_UPD(dd, D0, D1, D2, I0, I1, I2, c) { \
  bool l2 = (dd) < D2, l1 = (dd) < D1, l0 = (dd) < D0; \
  D2 = l1 ? D1 : (l2 ? (dd) : D2);  I2 = l1 ? I1 : (l2 ? (c) : I2); \
  D1 = l0 ? D0 : (l1 ? (dd) : D1);  I1 = l0 ? I0 : (l1 ? (c) : I1); \
  D0 = l0 ? (dd) : D0;              I0 = l0 ? (c) : I0; }

// ---------------- prep: P1 bf16 table + weight transposes + xyz1 SoA ----------------
__global__ void prep(const float* __restrict__ pc1,
                     const float* __restrict__ W1, const float* __restrict__ W2,
                     unsigned short* __restrict__ W1t, unsigned short* __restrict__ W2t,
                     float* __restrict__ soa, unsigned short* __restrict__ P1) {
  int tid = blockIdx.x * 256 + threadIdx.x;
  if (tid < 524288) {
    int r = tid >> 6, l = tid & 63;
    const float* src = pc1 + (size_t)r * 259 + 3 + l * 4;
    ushort4 v;
    v.x = f2bf(src[0]); v.y = f2bf(src[1]); v.z = f2bf(src[2]); v.w = f2bf(src[3]);
    *(ushort4*)(P1 + ((size_t)r << 8) + l * 4) = v;
  } else if (tid < 622592) {
    int id = tid - 524288;                     // W1t[n][k] = W1[k][n], 256x384
    int n = id / 384, k = id - n * 384;
    W1t[id] = f2bf(W1[k * 256 + n]);
  } else if (tid < 688128) {
    int id2 = tid - 622592;                    // W2t[n][k] = W2[k][n], 256x256
    int n = id2 >> 8, k = id2 & 255;
    W2t[id2] = f2bf(W2[k * 256 + n]);
  } else if (tid < 712704) {
    int id = tid - 688128;                     // soa[b][coord][r] = xyz1
    int b = id / 3072, rem = id - b * 3072;
    int coord = rem >> 10, r = rem & 1023;
    soa[id] = pc1[(size_t)b * (1024 * 259) + (size_t)r * 259 + coord];
  }
}

// ---------------- front: lane-owns-query 3-NN + inline interp ----------------
// 512 blocks x 512 threads; block owns 64 queries; lane = query, wave = 128-pt chunk.
// Points broadcast from LDS (3 b128 per quad serve 64 queries). Chunk partials
// merged in LDS with exact lexicographic INSERTs (partition-invariant selection).
__global__ __launch_bounds__(512, 2) void front(
    const float* __restrict__ pc2, const float* __restrict__ soa,
    const unsigned short* __restrict__ P1,
    unsigned short* __restrict__ A1, float* __restrict__ xyzo) {
#pragma clang fp contract(off)
  __shared__ __align__(16) float s3[3][1024];   // 12 KB SoA points
  __shared__ float md[8][64][3];                // 6 KB  chunk-partial dists
  __shared__ int   mj[8][64][3];                // 6 KB  chunk-partial idxs
  const int t = threadIdx.x;
  const int blk = (blockIdx.x & 7) * 64 + (blockIdx.x >> 3);   // 512 = 8*64 bijective
  const int b = blk >> 6;                       // batch (one per XCD)
  const int qg = blk & 63;                      // 64-query group
  const int wv = t >> 6, lane = t & 63;

  // stage SoA xyz1 (3072 f32 = 768 f32x4), coalesced
  {
    const f32x4* g = (const f32x4*)(soa + b * 3072);
    f32x4* ls = (f32x4*)&s3[0][0];
    ls[t] = g[t];
    if (t < 256) ls[512 + t] = g[512 + t];
  }
  __syncthreads();

  const int q = qg * 64 + lane;                 // query index within batch
  const size_t qrow = (size_t)b * 4096 + q;
  const float* qp = pc2 + qrow * 131;
  const float qx = qp[0], qy = qp[1], qz = qp[2];
  const f32x2 qx2 = {qx, qx}, qy2 = {qy, qy}, qz2 = {qz, qz};

  // 4 independent top-3 chains over this wave's 32-quad chunk
  float dA0 = 3.4e38f, dA1 = 3.4e38f, dA2 = 3.4e38f;  int iA0 = -1, iA1 = -1, iA2 = -1;
  float dB0 = 3.4e38f, dB1 = 3.4e38f, dB2 = 3.4e38f;  int iB0 = -1, iB1 = -1, iB2 = -1;
  float dC0 = 3.4e38f, dC1 = 3.4e38f, dC2 = 3.4e38f;  int iC0 = -1, iC1 = -1, iC2 = -1;
  float dD0 = 3.4e38f, dD1 = 3.4e38f, dD2 = 3.4e38f;  int iD0 = -1, iD1 = -1, iD2 = -1;

  const f32x4* sXf = (const f32x4*)&s3[0][0];
  const f32x4* sYf = (const f32x4*)&s3[1][0];
  const f32x4* sZf = (const f32x4*)&s3[2][0];

  #pragma unroll 8
  for (int it = 0; it < 32; ++it) {
    const int m = wv * 32 + it;                 // quad index, same for all lanes (broadcast)
    f32x4 xv = sXf[m], yv = sYf[m], zv = sZf[m];
    // packed exact math, numpy order: (dx*dx + dy*dy) + dz*dz, contract(off)
    f32x2 xlo = {xv[0], xv[1]}, xhi = {xv[2], xv[3]};
    f32x2 ylo = {yv[0], yv[1]}, yhi = {yv[2], yv[3]};
    f32x2 zlo = {zv[0], zv[1]}, zhi = {zv[2], zv[3]};
    f32x2 dxl = qx2 - xlo, dyl = qy2 - ylo, dzl = qz2 - zlo;
    f32x2 dxh = qx2 - xhi, dyh = qy2 - yhi, dzh = qz2 - zhi;
    f32x2 dl = (dxl * dxl + dyl * dyl) + dzl * dzl;
    f32x2 dh = (dxh * dxh + dyh * dyh) + dzh * dzh;
    const int c0 = m * 4;
    CHAIN_UPD(dl[0], dA0, dA1, dA2, iA0, iA1, iA2, c0)
    CHAIN_UPD(dl[1], dB0, dB1, dB2, iB0, iB1, iB2, c0 + 1)
    CHAIN_UPD(dh[0], dC0, dC1, dC2, iC0, iC1, iC2, c0 + 2)
    CHAIN_UPD(dh[1], dD0, dD1, dD2, iD0, iD1, iD2, c0 + 3)
  }

  // merge chains B,C,D into A (exact lexicographic) -> chunk partial
  float d0 = dA0, d1 = dA1, d2v = dA2;  int i0 = iA0, i1 = iA1, i2 = iA2;
  INSERT(dB0, iB0) INSERT(dB1, iB1) INSERT(dB2, iB2)
  INSERT(dC0, iC0) INSERT(dC1, iC1) INSERT(dC2, iC2)
  INSERT(dD0, iD0) INSERT(dD1, iD1) INSERT(dD2, iD2)

  md[wv][lane][0] = d0;  md[wv][lane][1] = d1;  md[wv][lane][2] = d2v;
  mj[wv][lane][0] = i0;  mj[wv][lane][1] = i1;  mj[wv][lane][2] = i2;
  __syncthreads();

  // every thread merges all 8 chunk-partials for its query (redundant across waves,
  // so each (wv,lane) thread ends holding idx/weights for its interp slice)
  d0 = md[0][lane][0]; d1 = md[0][lane][1]; d2v = md[0][lane][2];
  i0 = mj[0][lane][0]; i1 = mj[0][lane][1]; i2 = mj[0][lane][2];
  #pragma unroll
  for (int c = 1; c < 8; ++c) {
    float e0 = md[c][lane][0], e1 = md[c][lane][1], e2 = md[c][lane][2];
    int   j0 = mj[c][lane][0], j1 = mj[c][lane][1], j2 = mj[c][lane][2];
    INSERT(e0, j0) INSERT(e1, j1) INSERT(e2, j2)
  }

  // weights (exact reference order)
  float t0 = fmaxf(d0, 1e-7f), t1 = fmaxf(d1, 1e-7f), t2 = fmaxf(d2v, 1e-7f);
  float r0 = 1.0f / t0, r1 = 1.0f / t1, r2 = 1.0f / t2;
  float nrm = (r0 + r1) + r2;
  float w0v = r0 / nrm, w1v = r1 / nrm, w2v = r2 / nrm;

  if (wv == 0) {
    xyzo[qrow * 3 + 0] = qx; xyzo[qrow * 3 + 1] = qy; xyzo[qrow * 3 + 2] = qz;
  }

  // --- inline interp from P1 bf16: thread covers cols [wv*32, +32) ---
  const unsigned short* P1b = P1 + ((size_t)b << 18);
  const uint4* g0 = (const uint4*)(P1b + (i0 << 8) + wv * 32);
  const uint4* g1 = (const uint4*)(P1b + (i1 << 8) + wv * 32);
  const uint4* g2 = (const uint4*)(P1b + (i2 << 8) + wv * 32);
  unsigned short* arow = A1 + qrow * 384 + wv * 32;
  #pragma unroll
  for (int h = 0; h < 4; ++h) {
    uint4 u0 = g0[h], u1 = g1[h], u2 = g2[h];
    unsigned ov[4];
    const unsigned* a0 = (const unsigned*)&u0;
    const unsigned* a1 = (const unsigned*)&u1;
    const unsigned* a2 = (const unsigned*)&u2;
    #pragma unroll
    for (int c = 0; c < 4; ++c) {
      float lo = fmaf(w2v, bflo(a2[c]), fmaf(w1v, bflo(a1[c]), w0v * bflo(a0[c])));
      float hi = fmaf(w2v, bfhi(a2[c]), fmaf(w1v, bfhi(a1[c]), w0v * bfhi(a0[c])));
      ov[c] = (unsigned)f2bf(lo) | ((unsigned)f2bf(hi) << 16);
    }
    *(uint4*)(arow + h * 8) = *(const uint4*)ov;
  }
  // --- pc2 feature cols: thread covers A1 cols [256+wv*16, +16) ---
  const float* gp = qp + 3 + wv * 16;
  unsigned short* arow2 = A1 + qrow * 384 + 256 + wv * 16;
  #pragma unroll
  for (int c4 = 0; c4 < 4; ++c4) {
    f4a v = *(const f4a*)(gp + c4 * 4);
    ushort4 ov;
    ov.x = f2bf(v.x); ov.y = f2bf(v.y); ov.z = f2bf(v.z); ov.w = f2bf(v.w);
    *(ushort4*)(arow2 + c4 * 4) = ov;
  }
}

// ---------------- fused two-layer MFMA GEMM (R7 160KB version, best measured) ----------------
__global__ __launch_bounds__(512, 2) void fused_gemm(
    const unsigned short* __restrict__ A1, const unsigned short* __restrict__ W1t,
    const unsigned short* __restrict__ W2t, const float* __restrict__ b1,
    const float* __restrict__ b2, float* __restrict__ out) {
  extern __shared__ char lds[];
  char* Hbuf = lds;                       // [0, 64K): H tile 128x256 bf16, row stride 512B
  char* Bb[2] = { lds + 65536, lds + 98304 };
  char* Ab[2] = { lds + 131072, lds + 147456 };

  const int t = threadIdx.x, lane = t & 63, wv = t >> 6;
  const int wm = wv >> 2, wn = wv & 3;
  const int m0 = blockIdx.x * 128;

  const int arow = t >> 2, as0 = (t & 3) * 2;
  const int brow = t >> 1, bs0 = (t & 1) * 4;
  const unsigned short* gA  = A1  + (size_t)(m0 + arow) * 384 + as0 * 8;
  const unsigned short* gB1 = W1t + (size_t)brow * 384 + bs0 * 8;
  const unsigned short* gW2 = W2t + (size_t)brow * 256 + bs0 * 8;
  int awo[2], bwo[4];
  #pragma unroll
  for (int j = 0; j < 2; ++j)
    awo[j] = arow * 128 + (((as0 + j) * 16) ^ ((arow & 7) << 4));
  #pragma unroll
  for (int j = 0; j < 4; ++j)
    bwo[j] = brow * 128 + (((bs0 + j) * 16) ^ ((brow & 7) << 4));

  f32x4 zero = {0.f, 0.f, 0.f, 0.f};
  f32x4 acc[4][4];
  #pragma unroll
  for (int i = 0; i < 4; ++i)
    #pragma unroll
    for (int j = 0; j < 4; ++j) acc[i][j] = zero;

  f32x4 ra[2], rb[4];
  #pragma unroll
  for (int j = 0; j < 2; ++j) ra[j] = *(const f32x4*)(const void*)(gA + j * 8);
  #pragma unroll
  for (int j = 0; j < 4; ++j) rb[j] = *(const f32x4*)(const void*)(gB1 + j * 8);
  #pragma unroll
  for (int j = 0; j < 2; ++j) *(f32x4*)(void*)(Ab[0] + awo[j]) = ra[j];
  #pragma unroll
  for (int j = 0; j < 4; ++j) *(f32x4*)(void*)(Bb[0] + bwo[j]) = rb[j];
  __syncthreads();

  int cur = 0;
  #pragma unroll
  for (int kt = 0; kt < 6; ++kt) {
    if (kt < 5) {
      #pragma unroll
      for (int j = 0; j < 2; ++j) ra[j] = *(const f32x4*)(const void*)(gA + (kt + 1) * 64 + j * 8);
      #pragma unroll
      for (int j = 0; j < 4; ++j) rb[j] = *(const f32x4*)(const void*)(gB1 + (kt + 1) * 64 + j * 8);
    }
    #pragma unroll
    for (int ks = 0; ks < 2; ++ks) {
      bf16x8 af[4], bfr[4];
      const int sl = ks * 4 + (lane >> 4);
      #pragma unroll
      for (int i = 0; i < 4; ++i) {
        int ar = wm * 64 + i * 16 + (lane & 15);
        af[i] = *(const bf16x8*)(void*)(Ab[cur] + ar * 128 + ((sl * 16) ^ ((ar & 7) << 4)));
        int br = wn * 64 + i * 16 + (lane & 15);
        bfr[i] = *(const bf16x8*)(void*)(Bb[cur] + br * 128 + ((sl * 16) ^ ((br & 7) << 4)));
      }
      #pragma unroll
      for (int i = 0; i < 4; ++i)
        #pragma unroll
        for (int j = 0; j < 4; ++j)
          acc[i][j] = __builtin_amdgcn_mfma_f32_16x16x32_bf16(af[i], bfr[j], acc[i][j], 0, 0, 0);
    }
    if (kt < 5) {
      #pragma unroll
      for (int j = 0; j < 2; ++j) *(f32x4*)(void*)(Ab[cur ^ 1] + awo[j]) = ra[j];
      #pragma unroll
      for (int j = 0; j < 4; ++j) *(f32x4*)(void*)(Bb[cur ^ 1] + bwo[j]) = rb[j];
    }
    __syncthreads();
    cur ^= 1;
  }

  const int colb = wn * 64 + (lane & 15);
  const int rowb = wm * 64 + ((lane >> 4) << 2);
  #pragma unroll
  for (int ni = 0; ni < 4; ++ni) {
    float bv = b1[colb + ni * 16];
    #pragma unroll
    for (int mi = 0; mi < 4; ++mi) {
      #pragma unroll
      for (int r = 0; r < 4; ++r) {
        float v = fmaxf(acc[mi][ni][r] + bv, 0.0f);
        int row = rowb + mi * 16 + r, col = colb + ni * 16;
        *(unsigned short*)(Hbuf + row * 512 + ((col * 2) ^ ((row & 15) << 4))) = f2bf(v);
        acc[mi][ni][r] = 0.0f;
      }
    }
  }
  #pragma unroll
  for (int j = 0; j < 4; ++j) rb[j] = *(const f32x4*)(const void*)(gW2 + j * 8);
  #pragma unroll
  for (int j = 0; j < 4; ++j) *(f32x4*)(void*)(Bb[0] + bwo[j]) = rb[j];
  __syncthreads();

  cur = 0;
  #pragma unroll
  for (int kt = 0; kt < 4; ++kt) {
    if (kt < 3) {
      #pragma unroll
      for (int j = 0; j < 4; ++j) rb[j] = *(const f32x4*)(const void*)(gW2 + (kt + 1) * 64 + j * 8);
    }
    #pragma unroll
    for (int ks = 0; ks < 2; ++ks) {
      bf16x8 af[4], bfr[4];
      const int sl = ks * 4 + (lane >> 4);
      #pragma unroll
      for (int i = 0; i < 4; ++i) {
        int hr = wm * 64 + i * 16 + (lane & 15);
        af[i] = *(const bf16x8*)(void*)(Hbuf + hr * 512 + ((kt * 128 + sl * 16) ^ ((hr & 15) << 4)));
        int wr = wn * 64 + i * 16 + (lane & 15);
        bfr[i] = *(const bf16x8*)(void*)(Bb[cur] + wr * 128 + ((sl * 16) ^ ((wr & 7) << 4)));
      }
      #pragma unroll
      for (int i = 0; i < 4; ++i)
        #pragma unroll
        for (int j = 0; j < 4; ++j)
          acc[i][j] = __builtin_amdgcn_mfma_f32_16x16x32_bf16(af[i], bfr[j], acc[i][j], 0, 0, 0);
    }
    if (kt < 3) {
      #pragma unroll
      for (int j = 0; j < 4; ++j) *(f32x4*)(void*)(Bb[cur ^ 1] + bwo[j]) = rb[j];
    }
    __syncthreads();
    cur ^= 1;
  }

  #pragma unroll
  for (int ni = 0; ni < 4; ++ni) {
    float bv = b2[colb + ni * 16];
    #pragma unroll
    for (int mi = 0; mi < 4; ++mi) {
      #pragma unroll
      for (int r = 0; r < 4; ++r) {
        float v = fmaxf(acc[mi][ni][r] + bv, 0.0f);
        int row = rowb + mi * 16 + r, col = colb + ni * 16;
        *(float*)(lds + row * 1024 + ((col * 4) ^ ((row & 15) << 4))) = v;
      }
    }
  }
  __syncthreads();
  #pragma unroll
  for (int q = 0; q < 16; ++q) {
    int row = q * 8 + wv;
    f32x4 v = *(const f32x4*)(void*)(lds + row * 1024 + ((lane * 16) ^ ((row & 15) << 4)));
    *(f32x4*)(out + (size_t)(m0 + row) * 256 + lane * 4) = v;
  }
}

// ---------------- launch ----------------
extern "C" void kernel_launch(void* const* d_in, const int* in_sizes, int n_in,
                              void* d_out, int out_size, void* d_ws, size_t ws_size,
                              hipStream_t stream) {
  const float* pc1 = (const float*)d_in[0];
  const float* pc2 = (const float*)d_in[1];
  const float* W1  = (const float*)d_in[2];
  const float* b1  = (const float*)d_in[3];
  const float* W2  = (const float*)d_in[4];
  const float* b2  = (const float*)d_in[5];
  float* out = (float*)d_out;
  char* ws = (char*)d_ws;

  unsigned short* W1t = (unsigned short*)(ws + 0);        // 256x384 bf16
  unsigned short* W2t = (unsigned short*)(ws + 196608);   // 256x256 bf16
  float*          soa = (float*)(ws + 327680);            // 8x3x1024 f32
  unsigned short* P1  = (unsigned short*)(ws + 425984);   // 8x1024x256 bf16
  unsigned short* A1  = (unsigned short*)(ws + 4620288);  // 32768x384 bf16
  // ws usage ends at 29,786,112 bytes

  hipFuncSetAttribute((const void*)fused_gemm, hipFuncAttributeMaxDynamicSharedMemorySize, 163840);

  prep<<<2784, 256, 0, stream>>>(pc1, W1, W2, W1t, W2t, soa, P1);
  front<<<512, 512, 0, stream>>>(pc2, soa, P1, A1, out + OUT_H_ELEMS);
  fused_gemm<<<256, 512, 163840, stream>>>(A1, W1t, W2t, b1, b2, out);
}

// Round 11
// 59.447 us; speedup vs baseline: 1.3095x; 1.1074x over previous
//
#include <hip/hip_runtime.h>

// ---------------- types / helpers ----------------
using f32x4  = __attribute__((ext_vector_type(4))) float;
using f32x2  = __attribute__((ext_vector_type(2))) float;
using bf16x8 = __attribute__((ext_vector_type(8))) short;

struct __attribute__((packed, aligned(4))) f4a { float x, y, z, w; };  // 4B-aligned float4

__device__ __forceinline__ unsigned short f2bf(float x) {
  unsigned u = __float_as_uint(x);
  u += 0x7FFFu + ((u >> 16) & 1u);   // round-to-nearest-even
  return (unsigned short)(u >> 16);
}
__device__ __forceinline__ float bflo(unsigned u) { return __uint_as_float(u << 16); }
__device__ __forceinline__ float bfhi(unsigned u) { return __uint_as_float(u & 0xffff0000u); }

// pc1: (8,1024,259)  pc2: (8,4096,131)  W1:(384,256) b1:(256) W2:(256,256) b2:(256)
// out: h (8*4096*256 fp32) then xyz2 (8*4096*3 fp32)
#define OUT_H_ELEMS 8388608

// u64 key = (f32 bits of d << 32) | idx ; d >= 0 so unsigned-int order == (d, idx) lex order.
__device__ __forceinline__ unsigned long long dkey(float d, int i) {
  return ((unsigned long long)__float_as_uint(d) << 32) | (unsigned)i;
}
#define KINSERT(kk) { \
  bool L2 = (kk) < k2, L1 = (kk) < k1, L0 = (kk) < k0; \
  k2 = L1 ? k1 : (L2 ? (kk) : k2); \
  k1 = L0 ? k0 : (L1 ? (kk) : k1); \
  k0 = L0 ? (kk) : k0; }

#define CHAIN_UPD(dd, D0, D1, D2, I0, I1, I2, c) { \
  bool l2 = (dd) < D2, l1 = (dd) < D1, l0 = (dd) < D0; \
  D2 = l1 ? D1 : (l2 ? (dd) : D2);  I2 = l1 ? I1 : (l2 ? (c) : I2); \
  D1 = l0 ? D0 : (l1 ? (dd) : D1);  I1 = l0 ? I0 : (l1 ? (c) : I1); \
  D0 = l0 ? (dd) : D0;              I0 = l0 ? (c) : I0; }

// ---------------- prep: P1 bf16 table + weight transposes + xyz1 SoA (unchanged) ----------------
__global__ void prep(const float* __restrict__ pc1,
                     const float* __restrict__ W1, const float* __restrict__ W2,
                     unsigned short* __restrict__ W1t, unsigned short* __restrict__ W2t,
                     float* __restrict__ soa, unsigned short* __restrict__ P1) {
  int tid = blockIdx.x * 256 + threadIdx.x;
  if (tid < 524288) {
    int r = tid >> 6, l = tid & 63;
    const float* src = pc1 + (size_t)r * 259 + 3 + l * 4;
    ushort4 v;
    v.x = f2bf(src[0]); v.y = f2bf(src[1]); v.z = f2bf(src[2]); v.w = f2bf(src[3]);
    *(ushort4*)(P1 + ((size_t)r << 8) + l * 4) = v;
  } else if (tid < 622592) {
    int id = tid - 524288;                     // W1t[n][k] = W1[k][n], 256x384
    int n = id / 384, k = id - n * 384;
    W1t[id] = f2bf(W1[k * 256 + n]);
  } else if (tid < 688128) {
    int id2 = tid - 622592;                    // W2t[n][k] = W2[k][n], 256x256
    int n = id2 >> 8, k = id2 & 255;
    W2t[id2] = f2bf(W2[k * 256 + n]);
  } else if (tid < 712704) {
    int id = tid - 688128;                     // soa[b][coord][r] = xyz1
    int b = id / 3072, rem = id - b * 3072;
    int coord = rem >> 10, r = rem & 1023;
    soa[id] = pc1[(size_t)b * (1024 * 259) + (size_t)r * 259 + coord];
  }
}

// ---------------- front: 3-NN + inline interp + pc2 cols + xyz2 ----------------
// 2048 blocks x 256 threads; 16 queries/block, 16 lanes/query.
// launch_bounds(256,4): VGPR cap 128 so the compiler can pipeline LDS reads + gathers.
__global__ __launch_bounds__(256, 4) void front(
    const float* __restrict__ pc2, const float* __restrict__ soa,
    const unsigned short* __restrict__ P1,
    unsigned short* __restrict__ A1, float* __restrict__ xyzo) {
#pragma clang fp contract(off)
  __shared__ __align__(16) float s3[3][1024];
  const int t = threadIdx.x;
  const int blk = (blockIdx.x & 7) * 256 + (blockIdx.x >> 3);   // bijective (2048 = 8*256)
  const int b = blk >> 8;
  const int chunk = blk & 255;

  // --- stage SoA xyz1 into LDS: 3 coalesced f32x4 per thread ---
  const f32x4* gsoa = (const f32x4*)(soa + b * 3072);
  f32x4* ls = (f32x4*)&s3[0][0];
  #pragma unroll
  for (int j = 0; j < 3; ++j) ls[j * 256 + t] = gsoa[j * 256 + t];
  __syncthreads();

  const int q = chunk * 16 + (t >> 4);
  const int sub = t & 15;
  const size_t qrow = (size_t)b * 4096 + q;
  const float* qp = pc2 + qrow * 131;
  const float qx = qp[0], qy = qp[1], qz = qp[2];
  const f32x2 qx2 = {qx, qx}, qy2 = {qy, qy}, qz2 = {qz, qz};

  // 4 independent top-3 chains, one per element of each float4 quad
  float dA0 = 3.4e38f, dA1 = 3.4e38f, dA2 = 3.4e38f;  int iA0 = -1, iA1 = -1, iA2 = -1;
  float dB0 = 3.4e38f, dB1 = 3.4e38f, dB2 = 3.4e38f;  int iB0 = -1, iB1 = -1, iB2 = -1;
  float dC0 = 3.4e38f, dC1 = 3.4e38f, dC2 = 3.4e38f;  int iC0 = -1, iC1 = -1, iC2 = -1;
  float dD0 = 3.4e38f, dD1 = 3.4e38f, dD2 = 3.4e38f;  int iD0 = -1, iD1 = -1, iD2 = -1;

  const f32x4* sXf = (const f32x4*)&s3[0][0];
  const f32x4* sYf = (const f32x4*)&s3[1][0];
  const f32x4* sZf = (const f32x4*)&s3[2][0];

  #pragma unroll 4
  for (int it = 0; it < 16; ++it) {
    const int m = it * 16 + sub;       // quad index 0..255
    f32x4 xv = sXf[m], yv = sYf[m], zv = sZf[m];
    // packed exact math, numpy order: (dx*dx + dy*dy) + dz*dz, contract(off)
    f32x2 xlo = {xv[0], xv[1]}, xhi = {xv[2], xv[3]};
    f32x2 ylo = {yv[0], yv[1]}, yhi = {yv[2], yv[3]};
    f32x2 zlo = {zv[0], zv[1]}, zhi = {zv[2], zv[3]};
    f32x2 dxl = qx2 - xlo, dyl = qy2 - ylo, dzl = qz2 - zlo;
    f32x2 dxh = qx2 - xhi, dyh = qy2 - yhi, dzh = qz2 - zhi;
    f32x2 dl = (dxl * dxl + dyl * dyl) + dzl * dzl;
    f32x2 dh = (dxh * dxh + dyh * dyh) + dzh * dzh;
    const int c0 = m * 4;
    CHAIN_UPD(dl[0], dA0, dA1, dA2, iA0, iA1, iA2, c0)
    CHAIN_UPD(dl[1], dB0, dB1, dB2, iB0, iB1, iB2, c0 + 1)
    CHAIN_UPD(dh[0], dC0, dC1, dC2, iC0, iC1, iC2, c0 + 2)
    CHAIN_UPD(dh[1], dD0, dD1, dD2, iD0, iD1, iD2, c0 + 3)
  }

  // ---- merges via u64 (d,idx) keys: exact lexicographic, 1 cmp_u64 per level ----
  unsigned long long k0 = dkey(dA0, iA0), k1 = dkey(dA1, iA1), k2 = dkey(dA2, iA2);
  { unsigned long long kk;
    kk = dkey(dB0, iB0); KINSERT(kk)  kk = dkey(dB1, iB1); KINSERT(kk)  kk = dkey(dB2, iB2); KINSERT(kk)
    kk = dkey(dC0, iC0); KINSERT(kk)  kk = dkey(dC1, iC1); KINSERT(kk)  kk = dkey(dC2, iC2); KINSERT(kk)
    kk = dkey(dD0, iD0); KINSERT(kk)  kk = dkey(dD1, iD1); KINSERT(kk)  kk = dkey(dD2, iD2); KINSERT(kk)
  }
  // merge across the 16 lanes of this query; all lanes end identical
  #pragma unroll
  for (int stp = 1; stp <= 8; stp <<= 1) {
    unsigned long long e0 = __shfl_xor(k0, stp, 64);
    unsigned long long e1 = __shfl_xor(k1, stp, 64);
    unsigned long long e2 = __shfl_xor(k2, stp, 64);
    KINSERT(e0) KINSERT(e1) KINSERT(e2)
  }
  float d0 = __uint_as_float((unsigned)(k0 >> 32));
  float d1 = __uint_as_float((unsigned)(k1 >> 32));
  float d2v = __uint_as_float((unsigned)(k2 >> 32));
  const int i0 = (int)(k0 & 0xffffffffu);
  const int i1 = (int)(k1 & 0xffffffffu);
  const int i2 = (int)(k2 & 0xffffffffu);

  // weights (exact reference order)
  float t0 = fmaxf(d0, 1e-7f), t1 = fmaxf(d1, 1e-7f), t2 = fmaxf(d2v, 1e-7f);
  float r0 = 1.0f / t0, r1 = 1.0f / t1, r2 = 1.0f / t2;
  float nrm = (r0 + r1) + r2;
  float w0v = r0 / nrm, w1v = r1 / nrm, w2v = r2 / nrm;

  if (sub == 1) {
    xyzo[qrow * 3 + 0] = qx; xyzo[qrow * 3 + 1] = qy; xyzo[qrow * 3 + 2] = qz;
  }

  // --- inline interp from P1 bf16 (32B-aligned): lane covers cols [sub*16, +16) ---
  const unsigned short* P1b = P1 + ((size_t)b << 18);
  const uint4* g0 = (const uint4*)(P1b + (i0 << 8) + sub * 16);
  const uint4* g1 = (const uint4*)(P1b + (i1 << 8) + sub * 16);
  const uint4* g2 = (const uint4*)(P1b + (i2 << 8) + sub * 16);
  unsigned short* arow = A1 + qrow * 384 + sub * 16;
  #pragma unroll
  for (int h = 0; h < 2; ++h) {
    uint4 u0 = g0[h], u1 = g1[h], u2 = g2[h];
    unsigned ov[4];
    const unsigned* a0 = (const unsigned*)&u0;
    const unsigned* a1 = (const unsigned*)&u1;
    const unsigned* a2 = (const unsigned*)&u2;
    #pragma unroll
    for (int c = 0; c < 4; ++c) {
      float lo = fmaf(w2v, bflo(a2[c]), fmaf(w1v, bflo(a1[c]), w0v * bflo(a0[c])));
      float hi = fmaf(w2v, bfhi(a2[c]), fmaf(w1v, bfhi(a1[c]), w0v * bfhi(a0[c])));
      ov[c] = (unsigned)f2bf(lo) | ((unsigned)f2bf(hi) << 16);
    }
    *(uint4*)(arow + h * 8) = *(const uint4*)ov;
  }
  // --- pc2 feature cols: lane covers A1 cols [256+sub*8, +8) ---
  const float* gp = qp + 3 + sub * 8;
  unsigned short* arow2 = A1 + qrow * 384 + 256 + sub * 8;
  #pragma unroll
  for (int c4 = 0; c4 < 2; ++c4) {
    f4a v = *(const f4a*)(gp + c4 * 4);
    ushort4 ov;
    ov.x = f2bf(v.x); ov.y = f2bf(v.y); ov.z = f2bf(v.z); ov.w = f2bf(v.w);
    *(ushort4*)(arow2 + c4 * 4) = ov;
  }
}

// ---------------- fused two-layer MFMA GEMM (160KB version, best measured; unchanged) ----------------
__global__ __launch_bounds__(512, 2) void fused_gemm(
    const unsigned short* __restrict__ A1, const unsigned short* __restrict__ W1t,
    const unsigned short* __restrict__ W2t, const float* __restrict__ b1,
    const float* __restrict__ b2, float* __restrict__ out) {
  extern __shared__ char lds[];
  char* Hbuf = lds;                       // [0, 64K): H tile 128x256 bf16, row stride 512B
  char* Bb[2] = { lds + 65536, lds + 98304 };
  char* Ab[2] = { lds + 131072, lds + 147456 };

  const int t = threadIdx.x, lane = t & 63, wv = t >> 6;
  const int wm = wv >> 2, wn = wv & 3;
  const int m0 = blockIdx.x * 128;

  const int arow = t >> 2, as0 = (t & 3) * 2;
  const int brow = t >> 1, bs0 = (t & 1) * 4;
  const unsigned short* gA  = A1  + (size_t)(m0 + arow) * 384 + as0 * 8;
  const unsigned short* gB1 = W1t + (size_t)brow * 384 + bs0 * 8;
  const unsigned short* gW2 = W2t + (size_t)brow * 256 + bs0 * 8;
  int awo[2], bwo[4];
  #pragma unroll
  for (int j = 0; j < 2; ++j)
    awo[j] = arow * 128 + (((as0 + j) * 16) ^ ((arow & 7) << 4));
  #pragma unroll
  for (int j = 0; j < 4; ++j)
    bwo[j] = brow * 128 + (((bs0 + j) * 16) ^ ((brow & 7) << 4));

  f32x4 zero = {0.f, 0.f, 0.f, 0.f};
  f32x4 acc[4][4];
  #pragma unroll
  for (int i = 0; i < 4; ++i)
    #pragma unroll
    for (int j = 0; j < 4; ++j) acc[i][j] = zero;

  f32x4 ra[2], rb[4];
  #pragma unroll
  for (int j = 0; j < 2; ++j) ra[j] = *(const f32x4*)(const void*)(gA + j * 8);
  #pragma unroll
  for (int j = 0; j < 4; ++j) rb[j] = *(const f32x4*)(const void*)(gB1 + j * 8);
  #pragma unroll
  for (int j = 0; j < 2; ++j) *(f32x4*)(void*)(Ab[0] + awo[j]) = ra[j];
  #pragma unroll
  for (int j = 0; j < 4; ++j) *(f32x4*)(void*)(Bb[0] + bwo[j]) = rb[j];
  __syncthreads();

  int cur = 0;
  #pragma unroll
  for (int kt = 0; kt < 6; ++kt) {
    if (kt < 5) {
      #pragma unroll
      for (int j = 0; j < 2; ++j) ra[j] = *(const f32x4*)(const void*)(gA + (kt + 1) * 64 + j * 8);
      #pragma unroll
      for (int j = 0; j < 4; ++j) rb[j] = *(const f32x4*)(const void*)(gB1 + (kt + 1) * 64 + j * 8);
    }
    #pragma unroll
    for (int ks = 0; ks < 2; ++ks) {
      bf16x8 af[4], bfr[4];
      const int sl = ks * 4 + (lane >> 4);
      #pragma unroll
      for (int i = 0; i < 4; ++i) {
        int ar = wm * 64 + i * 16 + (lane & 15);
        af[i] = *(const bf16x8*)(void*)(Ab[cur] + ar * 128 + ((sl * 16) ^ ((ar & 7) << 4)));
        int br = wn * 64 + i * 16 + (lane & 15);
        bfr[i] = *(const bf16x8*)(void*)(Bb[cur] + br * 128 + ((sl * 16) ^ ((br & 7) << 4)));
      }
      #pragma unroll
      for (int i = 0; i < 4; ++i)
        #pragma unroll
        for (int j = 0; j < 4; ++j)
          acc[i][j] = __builtin_amdgcn_mfma_f32_16x16x32_bf16(af[i], bfr[j], acc[i][j], 0, 0, 0);
    }
    if (kt < 5) {
      #pragma unroll
      for (int j = 0; j < 2; ++j) *(f32x4*)(void*)(Ab[cur ^ 1] + awo[j]) = ra[j];
      #pragma unroll
      for (int j = 0; j < 4; ++j) *(f32x4*)(void*)(Bb[cur ^ 1] + bwo[j]) = rb[j];
    }
    __syncthreads();
    cur ^= 1;
  }

  const int colb = wn * 64 + (lane & 15);
  const int rowb = wm * 64 + ((lane >> 4) << 2);
  #pragma unroll
  for (int ni = 0; ni < 4; ++ni) {
    float bv = b1[colb + ni * 16];
    #pragma unroll
    for (int mi = 0; mi < 4; ++mi) {
      #pragma unroll
      for (int r = 0; r < 4; ++r) {
        float v = fmaxf(acc[mi][ni][r] + bv, 0.0f);
        int row = rowb + mi * 16 + r, col = colb + ni * 16;
        *(unsigned short*)(Hbuf + row * 512 + ((col * 2) ^ ((row & 15) << 4))) = f2bf(v);
        acc[mi][ni][r] = 0.0f;
      }
    }
  }
  #pragma unroll
  for (int j = 0; j < 4; ++j) rb[j] = *(const f32x4*)(const void*)(gW2 + j * 8);
  #pragma unroll
  for (int j = 0; j < 4; ++j) *(f32x4*)(void*)(Bb[0] + bwo[j]) = rb[j];
  __syncthreads();

  cur = 0;
  #pragma unroll
  for (int kt = 0; kt < 4; ++kt) {
    if (kt < 3) {
      #pragma unroll
      for (int j = 0; j < 4; ++j) rb[j] = *(const f32x4*)(const void*)(gW2 + (kt + 1) * 64 + j * 8);
    }
    #pragma unroll
    for (int ks = 0; ks < 2; ++ks) {
      bf16x8 af[4], bfr[4];
      const int sl = ks * 4 + (lane >> 4);
      #pragma unroll
      for (int i = 0; i < 4; ++i) {
        int hr = wm * 64 + i * 16 + (lane & 15);
        af[i] = *(const bf16x8*)(void*)(Hbuf + hr * 512 + ((kt * 128 + sl * 16) ^ ((hr & 15) << 4)));
        int wr = wn * 64 + i * 16 + (lane & 15);
        bfr[i] = *(const bf16x8*)(void*)(Bb[cur] + wr * 128 + ((sl * 16) ^ ((wr & 7) << 4)));
      }
      #pragma unroll
      for (int i = 0; i < 4; ++i)
        #pragma unroll
        for (int j = 0; j < 4; ++j)
          acc[i][j] = __builtin_amdgcn_mfma_f32_16x16x32_bf16(af[i], bfr[j], acc[i][j], 0, 0, 0);
    }
    if (kt < 3) {
      #pragma unroll
      for (int j = 0; j < 4; ++j) *(f32x4*)(void*)(Bb[cur ^ 1] + bwo[j]) = rb[j];
    }
    __syncthreads();
    cur ^= 1;
  }

  #pragma unroll
  for (int ni = 0; ni < 4; ++ni) {
    float bv = b2[colb + ni * 16];
    #pragma unroll
    for (int mi = 0; mi < 4; ++mi) {
      #pragma unroll
      for (int r = 0; r < 4; ++r) {
        float v = fmaxf(acc[mi][ni][r] + bv, 0.0f);
        int row = rowb + mi * 16 + r, col = colb + ni * 16;
        *(float*)(lds + row * 1024 + ((col * 4) ^ ((row & 15) << 4))) = v;
      }
    }
  }
  __syncthreads();
  #pragma unroll
  for (int q = 0; q < 16; ++q) {
    int row = q * 8 + wv;
    f32x4 v = *(const f32x4*)(void*)(lds + row * 1024 + ((lane * 16) ^ ((row & 15) << 4)));
    *(f32x4*)(out + (size_t)(m0 + row) * 256 + lane * 4) = v;
  }
}

// ---------------- launch ----------------
extern "C" void kernel_launch(void* const* d_in, const int* in_sizes, int n_in,
                              void* d_out, int out_size, void* d_ws, size_t ws_size,
                              hipStream_t stream) {
  const float* pc1 = (const float*)d_in[0];
  const float* pc2 = (const float*)d_in[1];
  const float* W1  = (const float*)d_in[2];
  const float* b1  = (const float*)d_in[3];
  const float* W2  = (const float*)d_in[4];
  const float* b2  = (const float*)d_in[5];
  float* out = (float*)d_out;
  char* ws = (char*)d_ws;

  unsigned short* W1t = (unsigned short*)(ws + 0);        // 256x384 bf16
  unsigned short* W2t = (unsigned short*)(ws + 196608);   // 256x256 bf16
  float*          soa = (float*)(ws + 327680);            // 8x3x1024 f32
  unsigned short* P1  = (unsigned short*)(ws + 425984);   // 8x1024x256 bf16
  unsigned short* A1  = (unsigned short*)(ws + 4620288);  // 32768x384 bf16
  // ws usage ends at 29,786,112 bytes

  hipFuncSetAttribute((const void*)fused_gemm, hipFuncAttributeMaxDynamicSharedMemorySize, 163840);

  prep<<<2784, 256, 0, stream>>>(pc1, W1, W2, W1t, W2t, soa, P1);
  front<<<2048, 256, 0, stream>>>(pc2, soa, P1, A1, out + OUT_H_ELEMS);
  fused_gemm<<<256, 512, 163840, stream>>>(A1, W1t, W2t, b1, b2, out);
}